// Round 2
// baseline (2160.219 us; speedup 1.0000x reference)
//
#include <hip/hip_runtime.h>

#define NROWS 8192
#define RPB   64
#define TPB   512
#define NBLK  128

// workspace layout (float offsets)
#define OFF_W1   0          // 1024
#define OFF_W2   1024       // 1024
#define OFF_WIN  2048       // 102*34 = 3468
#define OFF_WFC2 5516       // 1024
#define OFF_M    6540       // 32*34 = 1088
#define OFF_B12  7628       // 32
#define OFF_BIN  7660       // 102
#define OFF_B2   7762       // 32
#define OFF_BFC2 7794       // 32
#define OFF_LNG  7826       // 32
#define OFF_LNB  7858       // 32
#define OFF_QKV0 8192
#define QKVN     (NROWS*102)
#define OFF_QKV1 (OFF_QKV0 + QKVN)
#define OFF_HNEW (OFF_QKV1 + QKVN)   // NROWS*32

__global__ __launch_bounds__(256) void setup_kernel(
    const float* __restrict__ W_x2h, const float* __restrict__ b_x2h,
    const float* __restrict__ W_h2h, const float* __restrict__ b_h2h,
    const float* __restrict__ W_fc2, const float* __restrict__ b_fc2,
    const float* __restrict__ ln_g,  const float* __restrict__ ln_b,
    const float* __restrict__ W_fcsa,const float* __restrict__ b_fcsa,
    const float* __restrict__ W_in,  const float* __restrict__ b_in,
    const float* __restrict__ W_out, const float* __restrict__ b_out,
    float* __restrict__ ws)
{
  int t = blockIdx.x*blockDim.x + threadIdx.x;
  int stride = gridDim.x*blockDim.x;
  for (int i=t;i<1024;i+=stride) ws[OFF_W1+i]   = W_x2h[i];
  for (int i=t;i<1024;i+=stride) ws[OFF_W2+i]   = W_h2h[i];
  for (int i=t;i<3468;i+=stride) ws[OFF_WIN+i]  = W_in[i];
  for (int i=t;i<1024;i+=stride) ws[OFF_WFC2+i] = W_fc2[i];
  for (int i=t;i<32;i+=stride)   ws[OFF_B12+i]  = b_x2h[i] + b_h2h[i];
  for (int i=t;i<102;i+=stride)  ws[OFF_BIN+i]  = b_in[i];
  for (int i=t;i<32;i+=stride)   ws[OFF_BFC2+i] = b_fc2[i];
  for (int i=t;i<32;i+=stride)   ws[OFF_LNG+i]  = ln_g[i];
  for (int i=t;i<32;i+=stride)   ws[OFF_LNB+i]  = ln_b[i];
  // M = W_fcsa (32x34) @ W_out (34x34): M[j][f] = sum_e Wfcsa[j][e]*Wout[e][f]
  for (int idx=t; idx<1088; idx+=stride) {
    int j = idx/34, f = idx - j*34;
    float acc = 0.f;
    for (int e=0;e<34;++e)
      acc += W_fcsa[j*34+e] * W_out[e*34+f];
    ws[OFF_M+idx] = acc;
  }
  for (int j=t;j<32;j+=stride){
    float acc = b_fcsa[j];
    for (int e=0;e<34;++e) acc += W_fcsa[j*34+e] * b_out[e];
    ws[OFF_B2+j] = acc;
  }
}

// One launch = attention/update/pred of step (stepB) + rnn/qkv of step (stepA=stepB+1).
// lane (tid&63) = row within block's 64-row chunk; wave (tid>>6) = output split (wave-uniform
// so weight indices are scalar -> s_load).
__global__ __launch_bounds__(TPB) void step_kernel(
    const float* __restrict__ ws,
    const float* __restrict__ qkvR,     // qkv of step stepB (read)
    float* __restrict__ qkvW,           // qkv of step stepA (write)
    float* __restrict__ hnewG,          // tanh-state h_new (read: stepB's, then overwritten with stepA's)
    const float* __restrict__ x,
    float* __restrict__ out,
    int stepB, int stepA)
{
  const float* W1f   = ws + OFF_W1;
  const float* W2f   = ws + OFF_W2;
  const float* Winf  = ws + OFF_WIN;
  const float* Wfc2f = ws + OFF_WFC2;
  const float* Mf    = ws + OFF_M;
  const float* b12f  = ws + OFF_B12;
  const float* binf  = ws + OFF_BIN;
  const float* b2f   = ws + OFF_B2;
  const float* bfc2f = ws + OFF_BFC2;
  const float* lngf  = ws + OFF_LNG;
  const float* lnbf  = ws + OFF_LNB;

  __shared__ float sS[RPB][13];     // 9 scores, odd stride -> conflict-free
  __shared__ float sO[RPB][35];     // attention output (34)
  __shared__ float sHp[RPB][33];    // h' (post-attention state)
  __shared__ float sG[RPB][33];     // pre-LN fc2 output
  __shared__ float sPred[RPB][33];  // pred (next-step input)
  __shared__ float sHn[RPB][33];    // h_new (tanh output)

  const int tid = threadIdx.x;
  const int lr  = tid & 63;
  const int w   = tid >> 6;          // 0..7, wave-uniform
  const int r   = blockIdx.x * RPB + lr;
  const int b   = r >> 12;
  const int p   = r & 4095;
  const int gr  = p >> 6, gc = p & 63;
  // boundary-shifted window base (nr[0]+=1, nr[-1]-=1 etc.)
  const int br  = (gr < 1) ? 1 : ((gr > 62) ? 62 : gr);
  const int bc  = (gc < 1) ? 1 : ((gc > 62) ? 62 : gc);

  if (stepB >= 0) {
    // ---- scores: wave w does neighbor m=w (wave 0 also m=8) ----
    for (int m = w; m < 9; m += 8) {
      int dr = m/3 - 1, dc = (m - (m/3)*3) - 1;
      int qrow = (b<<12) + (br<<6) + bc;                 // query = gathered center (index 4)
      int nr_  = (b<<12) + ((br+dr)<<6) + (bc+dc);
      const float* qv = qkvR + (size_t)qrow*102;
      const float* kv = qkvR + (size_t)nr_*102 + 34;
      float acc = 0.f;
      #pragma unroll
      for (int e=0;e<34;++e) acc += qv[e]*kv[e];
      sS[lr][m] = acc * 0.1714985851425088f;             // 1/sqrt(34)
    }
    __syncthreads();
    // ---- softmax (redundant/lane) + o: wave w handles e = 5w..5w+4 ----
    if (w < 7) {
      float sc[9]; float mx = -1e30f;
      #pragma unroll
      for (int m=0;m<9;++m){ sc[m]=sS[lr][m]; mx=fmaxf(mx,sc[m]); }
      float sum=0.f;
      #pragma unroll
      for (int m=0;m<9;++m){ sc[m]=__expf(sc[m]-mx); sum+=sc[m]; }
      float inv = 1.f/sum;
      const int e0 = w*5;
      const int ne = (e0+5<=34)?5:(34-e0);
      float oacc[5] = {0.f,0.f,0.f,0.f,0.f};
      #pragma unroll
      for (int m=0;m<9;++m){
        int dr = m/3 - 1, dc = (m - (m/3)*3) - 1;
        int nr_ = (b<<12) + ((br+dr)<<6) + (bc+dc);
        const float* vv = qkvR + (size_t)nr_*102 + 68 + e0;
        float wm = sc[m]*inv;
        #pragma unroll
        for (int k=0;k<5;++k) if (k<ne) oacc[k] += wm*vv[k];
      }
      #pragma unroll
      for (int k=0;k<5;++k) if (k<ne) sO[lr][e0+k]=oacc[k];
    }
    __syncthreads();
    // ---- h' = h_new + o @ M^T + b2 : wave w -> j = 4w..4w+3 ----
    {
      const int j0 = w*4;
      float a[4];
      #pragma unroll
      for (int jj=0;jj<4;++jj) a[jj] = b2f[j0+jj];
      #pragma unroll
      for (int e=0;e<34;++e){
        float ov = sO[lr][e];
        #pragma unroll
        for (int jj=0;jj<4;++jj) a[jj] += ov * Mf[(j0+jj)*34+e];
      }
      #pragma unroll
      for (int jj=0;jj<4;++jj)
        sHp[lr][j0+jj] = hnewG[(size_t)r*32 + j0+jj] + a[jj];
    }
    __syncthreads();
    // ---- g = h' @ Wfc2^T + b ----
    {
      const int j0 = w*4;
      float g[4];
      #pragma unroll
      for (int jj=0;jj<4;++jj) g[jj] = bfc2f[j0+jj];
      #pragma unroll
      for (int i=0;i<32;++i){
        float hv = sHp[lr][i];
        #pragma unroll
        for (int jj=0;jj<4;++jj) g[jj] += hv * Wfc2f[(j0+jj)*32+i];
      }
      #pragma unroll
      for (int jj=0;jj<4;++jj) sG[lr][j0+jj]=g[jj];
    }
    __syncthreads();
    // ---- layernorm + write pred ----
    {
      float mu=0.f;
      #pragma unroll
      for (int i=0;i<32;++i) mu += sG[lr][i];
      mu *= 0.03125f;
      float var=0.f;
      #pragma unroll
      for (int i=0;i<32;++i){ float d=sG[lr][i]-mu; var += d*d; }
      var *= 0.03125f;
      float rs = rsqrtf(var + 1e-5f);
      const int j0 = w*4;
      #pragma unroll
      for (int jj=0;jj<4;++jj){
        int j=j0+jj;
        float pv = (sG[lr][j]-mu)*rs*lngf[j] + lnbf[j];
        sPred[lr][j]=pv;
        out[((size_t)stepB*NROWS + r)*32 + j] = pv;
      }
    }
    __syncthreads();
  } else {
    // step 0: h' = 0
    const int j0 = w*4;
    #pragma unroll
    for (int jj=0;jj<4;++jj) sHp[lr][j0+jj]=0.f;
    __syncthreads();
  }

  if (stepA >= 0) {
    // ---- h_new = tanh(inp@W1^T + h'@W2^T + b) : wave w -> j = 4w..4w+3 ----
    float xr[32];
    if (stepA < 10) {
      const float* xp = x + ((size_t)stepA*NROWS + r)*32;
      #pragma unroll
      for (int i=0;i<32;++i) xr[i]=xp[i];
    } else {
      #pragma unroll
      for (int i=0;i<32;++i) xr[i]=sPred[lr][i];
    }
    float hp[32];
    #pragma unroll
    for (int i=0;i<32;++i) hp[i]=sHp[lr][i];
    const int j0 = w*4;
    float a[4];
    #pragma unroll
    for (int jj=0;jj<4;++jj) a[jj]=b12f[j0+jj];
    #pragma unroll
    for (int i=0;i<32;++i){
      float xv=xr[i], hv=hp[i];
      #pragma unroll
      for (int jj=0;jj<4;++jj)
        a[jj] += xv*W1f[(j0+jj)*32+i] + hv*W2f[(j0+jj)*32+i];
    }
    #pragma unroll
    for (int jj=0;jj<4;++jj){
      float tv = tanhf(a[jj]);
      sHn[lr][j0+jj]=tv;
      hnewG[(size_t)r*32+j0+jj]=tv;
    }
    __syncthreads();
    // ---- qkv = [h_new, pl] @ W_in^T + b_in : wave w -> e = 13w..13w+12 ----
    float hn[32];
    #pragma unroll
    for (int f=0;f<32;++f) hn[f]=sHn[lr][f];
    const float pl0 = gr*0.015625f, pl1 = gc*0.015625f;
    const int e0 = w*13;
    #pragma unroll
    for (int k=0;k<13;++k){
      int e = e0+k;
      if (e < 102) {
        float acc = binf[e];
        #pragma unroll
        for (int f=0;f<32;++f) acc += hn[f]*Winf[e*34+f];
        acc += pl0*Winf[e*34+32] + pl1*Winf[e*34+33];
        qkvW[(size_t)r*102+e] = acc;
      }
    }
  }
}

extern "C" void kernel_launch(void* const* d_in, const int* in_sizes, int n_in,
                              void* d_out, int out_size, void* d_ws, size_t ws_size,
                              hipStream_t stream) {
  const float* x     = (const float*)d_in[0];
  const float* W_x2h = (const float*)d_in[1];
  const float* b_x2h = (const float*)d_in[2];
  const float* W_h2h = (const float*)d_in[3];
  const float* b_h2h = (const float*)d_in[4];
  const float* W_fc2 = (const float*)d_in[5];
  const float* b_fc2 = (const float*)d_in[6];
  const float* ln_g  = (const float*)d_in[7];
  const float* ln_b  = (const float*)d_in[8];
  const float* W_fcsa= (const float*)d_in[9];
  const float* b_fcsa= (const float*)d_in[10];
  const float* W_in  = (const float*)d_in[11];
  const float* b_in  = (const float*)d_in[12];
  const float* W_out = (const float*)d_in[13];
  const float* b_out = (const float*)d_in[14];
  float* ws = (float*)d_ws;
  float* out = (float*)d_out;

  setup_kernel<<<8, 256, 0, stream>>>(W_x2h,b_x2h,W_h2h,b_h2h,W_fc2,b_fc2,ln_g,ln_b,
                                      W_fcsa,b_fcsa,W_in,b_in,W_out,b_out, ws);
  for (int i=0;i<60;++i){
    int stepB = i-1;
    int stepA = (i<=58)? i : -1;
    const float* qR = ws + OFF_QKV0 + (size_t)((i+1)&1)*QKVN;  // qkv of step i-1
    float*       qW = ws + OFF_QKV0 + (size_t)(i&1)*QKVN;      // qkv of step i
    step_kernel<<<NBLK, TPB, 0, stream>>>(ws, qR, qW, ws+OFF_HNEW, x, out, stepB, stepA);
  }
}

// Round 3
// 1750.212 us; speedup vs baseline: 1.2343x; 1.2343x over previous
//
#include <hip/hip_runtime.h>

#define NROWS 8192
#define RPB   64
#define TPB   512
#define NBLK  128

// workspace layout (float offsets)
#define OFF_W1   0          // 1024
#define OFF_W2   1024       // 1024
#define OFF_WIN  2048       // 102*34 = 3468
#define OFF_WFC2 5516       // 1024
#define OFF_M    6540       // 32*34 = 1088
#define OFF_B12  7628       // 32
#define OFF_BIN  7660       // 102
#define OFF_B2   7762       // 32
#define OFF_BFC2 7794       // 32
#define OFF_LNG  7826       // 32
#define OFF_LNB  7858       // 32
#define OFF_QKV0 8192
#define QKVN     (NROWS*102)          // feature-major: qkv[e][row]
#define OFF_QKV1 (OFF_QKV0 + QKVN)
#define OFF_HNEW (OFF_QKV1 + QKVN)   // feature-major: hnew[j][row], 32*NROWS

__global__ __launch_bounds__(256) void setup_kernel(
    const float* __restrict__ W_x2h, const float* __restrict__ b_x2h,
    const float* __restrict__ W_h2h, const float* __restrict__ b_h2h,
    const float* __restrict__ W_fc2, const float* __restrict__ b_fc2,
    const float* __restrict__ ln_g,  const float* __restrict__ ln_b,
    const float* __restrict__ W_fcsa,const float* __restrict__ b_fcsa,
    const float* __restrict__ W_in,  const float* __restrict__ b_in,
    const float* __restrict__ W_out, const float* __restrict__ b_out,
    float* __restrict__ ws)
{
  int t = blockIdx.x*blockDim.x + threadIdx.x;
  int stride = gridDim.x*blockDim.x;
  for (int i=t;i<1024;i+=stride) ws[OFF_W1+i]   = W_x2h[i];
  for (int i=t;i<1024;i+=stride) ws[OFF_W2+i]   = W_h2h[i];
  for (int i=t;i<3468;i+=stride) ws[OFF_WIN+i]  = W_in[i];
  for (int i=t;i<1024;i+=stride) ws[OFF_WFC2+i] = W_fc2[i];
  for (int i=t;i<32;i+=stride)   ws[OFF_B12+i]  = b_x2h[i] + b_h2h[i];
  for (int i=t;i<102;i+=stride)  ws[OFF_BIN+i]  = b_in[i];
  for (int i=t;i<32;i+=stride)   ws[OFF_BFC2+i] = b_fc2[i];
  for (int i=t;i<32;i+=stride)   ws[OFF_LNG+i]  = ln_g[i];
  for (int i=t;i<32;i+=stride)   ws[OFF_LNB+i]  = ln_b[i];
  // M = W_fcsa (32x34) @ W_out (34x34)
  for (int idx=t; idx<1088; idx+=stride) {
    int j = idx/34, f = idx - j*34;
    float acc = 0.f;
    for (int e=0;e<34;++e)
      acc += W_fcsa[j*34+e] * W_out[e*34+f];
    ws[OFF_M+idx] = acc;
  }
  for (int j=t;j<32;j+=stride){
    float acc = b_fcsa[j];
    for (int e=0;e<34;++e) acc += W_fcsa[j*34+e] * b_out[e];
    ws[OFF_B2+j] = acc;
  }
}

// One launch = attention/update/pred of step stepB + tanh-rnn/qkv of step stepA=stepB+1.
// lane (tid&63) = row; wave (tid>>6) = feature-group (wave-uniform -> weights via s_load).
// qkv / hnew are FEATURE-MAJOR [feat][NROWS] so all global access is lane-coalesced.
__global__ __launch_bounds__(TPB) void step_kernel(
    const float* __restrict__ ws,
    const float* __restrict__ qkvR,     // qkv of step stepB (read)
    float* __restrict__ qkvW,           // qkv of step stepA (write)
    float* __restrict__ hnewG,          // feature-major tanh-state
    const float* __restrict__ x,
    float* __restrict__ out,
    int stepB, int stepA)
{
  const float* W1f   = ws + OFF_W1;
  const float* W2f   = ws + OFF_W2;
  const float* Winf  = ws + OFF_WIN;
  const float* Wfc2f = ws + OFF_WFC2;
  const float* Mf    = ws + OFF_M;
  const float* b12f  = ws + OFF_B12;
  const float* binf  = ws + OFF_BIN;
  const float* b2f   = ws + OFF_B2;
  const float* bfc2f = ws + OFF_BFC2;
  const float* lngf  = ws + OFF_LNG;
  const float* lnbf  = ws + OFF_LNB;

  __shared__ float sS[RPB][13];     // 9 scores
  __shared__ float sO[RPB][35];     // attention output (34)
  __shared__ float sHp[RPB][33];    // h' (post-attention state)
  __shared__ float sG[RPB][33];     // pre-LN fc2 output
  __shared__ float sPred[RPB][33];  // pred (next-step input)
  __shared__ float sHn[RPB][33];    // h_new (tanh output)
  __shared__ float sX[RPB][33];     // staged x chunk (steps 0..9)

  const int tid = threadIdx.x;
  const int lr  = tid & 63;
  const int w   = tid >> 6;          // 0..7, wave-uniform
  const int base= blockIdx.x * RPB;
  const int r   = base + lr;
  const int b   = r >> 12;
  const int p   = r & 4095;
  const int gr  = p >> 6, gc = p & 63;
  const int br  = (gr < 1) ? 1 : ((gr > 62) ? 62 : gr);
  const int bc  = (gc < 1) ? 1 : ((gc > 62) ? 62 : gc);

  if (stepB >= 0) {
    // ---- scores: wave w does neighbor m=w (wave 0 also m=8) ----
    const int qrow = (b<<12) + (br<<6) + bc;           // query = gathered center
    for (int m = w; m < 9; m += 8) {
      int dr = m/3 - 1, dc = (m - (m/3)*3) - 1;
      int nr_  = (b<<12) + ((br+dr)<<6) + (bc+dc);
      float acc = 0.f;
      #pragma unroll
      for (int e=0;e<34;++e)
        acc += qkvR[(size_t)e*NROWS + qrow] * qkvR[(size_t)(34+e)*NROWS + nr_];
      sS[lr][m] = acc * 0.1714985851425088f;           // 1/sqrt(34)
    }
    __syncthreads();
    // ---- softmax (redundant per wave) + o: wave w handles e = 5w.. ----
    if (w < 7) {
      float sc[9]; float mx = -1e30f;
      #pragma unroll
      for (int m=0;m<9;++m){ sc[m]=sS[lr][m]; mx=fmaxf(mx,sc[m]); }
      float sum=0.f;
      #pragma unroll
      for (int m=0;m<9;++m){ sc[m]=__expf(sc[m]-mx); sum+=sc[m]; }
      float inv = 1.f/sum;
      const int e0 = w*5;
      const int ne = (e0+5<=34)?5:(34-e0);
      float oacc[5] = {0.f,0.f,0.f,0.f,0.f};
      #pragma unroll
      for (int m=0;m<9;++m){
        int dr = m/3 - 1, dc = (m - (m/3)*3) - 1;
        int nr_ = (b<<12) + ((br+dr)<<6) + (bc+dc);
        float wm = sc[m]*inv;
        #pragma unroll
        for (int k=0;k<5;++k)
          if (k<ne) oacc[k] += wm * qkvR[(size_t)(68+e0+k)*NROWS + nr_];
      }
      #pragma unroll
      for (int k=0;k<5;++k) if (k<ne) sO[lr][e0+k]=oacc[k];
    }
    __syncthreads();
    // ---- h' = h_new + o @ M^T + b2 : wave w -> j = 4w..4w+3 ----
    {
      const int j0 = w*4;
      float a[4];
      #pragma unroll
      for (int jj=0;jj<4;++jj) a[jj] = b2f[j0+jj];
      #pragma unroll
      for (int e=0;e<34;++e){
        float ov = sO[lr][e];
        #pragma unroll
        for (int jj=0;jj<4;++jj) a[jj] += ov * Mf[(j0+jj)*34+e];
      }
      #pragma unroll
      for (int jj=0;jj<4;++jj)
        sHp[lr][j0+jj] = hnewG[(size_t)(j0+jj)*NROWS + r] + a[jj];
    }
    __syncthreads();
    // ---- g = h' @ Wfc2^T + b ----
    {
      const int j0 = w*4;
      float g[4];
      #pragma unroll
      for (int jj=0;jj<4;++jj) g[jj] = bfc2f[j0+jj];
      #pragma unroll
      for (int i=0;i<32;++i){
        float hv = sHp[lr][i];
        #pragma unroll
        for (int jj=0;jj<4;++jj) g[jj] += hv * Wfc2f[(j0+jj)*32+i];
      }
      #pragma unroll
      for (int jj=0;jj<4;++jj) sG[lr][j0+jj]=g[jj];
    }
    __syncthreads();
    // ---- layernorm -> sPred ----
    {
      float mu=0.f;
      #pragma unroll
      for (int i=0;i<32;++i) mu += sG[lr][i];
      mu *= 0.03125f;
      float var=0.f;
      #pragma unroll
      for (int i=0;i<32;++i){ float d=sG[lr][i]-mu; var += d*d; }
      var *= 0.03125f;
      float rs = rsqrtf(var + 1e-5f);
      const int j0 = w*4;
      #pragma unroll
      for (int jj=0;jj<4;++jj){
        int j=j0+jj;
        sPred[lr][j] = (sG[lr][j]-mu)*rs*lngf[j] + lnbf[j];
      }
    }
    __syncthreads();
    // ---- coalesced out write (block chunk is 2048 contiguous floats) ----
    {
      size_t obase = ((size_t)stepB*NROWS + base)*32;
      #pragma unroll
      for (int it=0; it<4; ++it){
        int idx = tid + it*TPB;
        out[obase + idx] = sPred[idx>>5][idx&31];
      }
    }
  } else {
    // step 0: h' = 0
    const int j0 = w*4;
    #pragma unroll
    for (int jj=0;jj<4;++jj) sHp[lr][j0+jj]=0.f;
    __syncthreads();
  }

  if (stepA >= 0) {
    // ---- stage x chunk (coalesced) if this step consumes observations ----
    if (stepA < 10) {
      size_t xbase = ((size_t)stepA*NROWS + base)*32;
      #pragma unroll
      for (int it=0; it<4; ++it){
        int idx = tid + it*TPB;
        sX[idx>>5][idx&31] = x[xbase + idx];
      }
    }
    __syncthreads();
    // ---- h_new = tanh(inp@W1^T + h'@W2^T + b) : wave w -> j = 4w..4w+3 ----
    const int j0 = w*4;
    float a[4];
    #pragma unroll
    for (int jj=0;jj<4;++jj) a[jj]=b12f[j0+jj];
    if (stepA < 10) {
      #pragma unroll
      for (int i=0;i<32;++i){
        float xv=sX[lr][i], hv=sHp[lr][i];
        #pragma unroll
        for (int jj=0;jj<4;++jj)
          a[jj] += xv*W1f[(j0+jj)*32+i] + hv*W2f[(j0+jj)*32+i];
      }
    } else {
      #pragma unroll
      for (int i=0;i<32;++i){
        float xv=sPred[lr][i], hv=sHp[lr][i];
        #pragma unroll
        for (int jj=0;jj<4;++jj)
          a[jj] += xv*W1f[(j0+jj)*32+i] + hv*W2f[(j0+jj)*32+i];
      }
    }
    #pragma unroll
    for (int jj=0;jj<4;++jj){
      float tv = tanhf(a[jj]);
      sHn[lr][j0+jj]=tv;
      hnewG[(size_t)(j0+jj)*NROWS + r]=tv;    // coalesced (feature-major)
    }
    __syncthreads();
    // ---- qkv = [h_new, pl] @ W_in^T + b_in : wave w -> e = 13w.. ----
    float hn[32];
    #pragma unroll
    for (int f=0;f<32;++f) hn[f]=sHn[lr][f];
    const float pl0 = gr*0.015625f, pl1 = gc*0.015625f;
    const int e0 = w*13;
    #pragma unroll
    for (int k=0;k<13;++k){
      int e = e0+k;
      if (e < 102) {
        float acc = binf[e];
        #pragma unroll
        for (int f=0;f<32;++f) acc += hn[f]*Winf[e*34+f];
        acc += pl0*Winf[e*34+32] + pl1*Winf[e*34+33];
        qkvW[(size_t)e*NROWS + r] = acc;       // coalesced (feature-major)
      }
    }
  }
}

extern "C" void kernel_launch(void* const* d_in, const int* in_sizes, int n_in,
                              void* d_out, int out_size, void* d_ws, size_t ws_size,
                              hipStream_t stream) {
  const float* x     = (const float*)d_in[0];
  const float* W_x2h = (const float*)d_in[1];
  const float* b_x2h = (const float*)d_in[2];
  const float* W_h2h = (const float*)d_in[3];
  const float* b_h2h = (const float*)d_in[4];
  const float* W_fc2 = (const float*)d_in[5];
  const float* b_fc2 = (const float*)d_in[6];
  const float* ln_g  = (const float*)d_in[7];
  const float* ln_b  = (const float*)d_in[8];
  const float* W_fcsa= (const float*)d_in[9];
  const float* b_fcsa= (const float*)d_in[10];
  const float* W_in  = (const float*)d_in[11];
  const float* b_in  = (const float*)d_in[12];
  const float* W_out = (const float*)d_in[13];
  const float* b_out = (const float*)d_in[14];
  float* ws = (float*)d_ws;
  float* out = (float*)d_out;

  setup_kernel<<<8, 256, 0, stream>>>(W_x2h,b_x2h,W_h2h,b_h2h,W_fc2,b_fc2,ln_g,ln_b,
                                      W_fcsa,b_fcsa,W_in,b_in,W_out,b_out, ws);
  for (int i=0;i<60;++i){
    int stepB = i-1;
    int stepA = (i<=58)? i : -1;
    const float* qR = ws + OFF_QKV0 + (size_t)((i+1)&1)*QKVN;  // qkv of step i-1
    float*       qW = ws + OFF_QKV0 + (size_t)(i&1)*QKVN;      // qkv of step i
    step_kernel<<<NBLK, TPB, 0, stream>>>(ws, qR, qW, ws+OFF_HNEW, x, out, stepB, stepA);
  }
}

// Round 4
// 1192.643 us; speedup vs baseline: 1.8113x; 1.4675x over previous
//
#include <hip/hip_runtime.h>

#define NROWS 8192
#define RPB   64
#define TPB   512
#define NBLK  128

// workspace layout (float offsets)
#define OFF_W1   0          // 1024
#define OFF_W2   1024       // 1024
#define OFF_WIN  2048       // 102*34 = 3468
#define OFF_WFC2 5516       // 1024
#define OFF_M    6540       // 32*34 = 1088
#define OFF_B12  7628       // 32
#define OFF_BIN  7660       // 102
#define OFF_B2   7762       // 32
#define OFF_BFC2 7794       // 32
#define OFF_LNG  7826       // 32
#define OFF_LNB  7858       // 32
#define OFF_QKV0 8192
#define QKVN     (NROWS*102)          // feature-major: qkv[e][row]
#define OFF_QKV1 (OFF_QKV0 + QKVN)
#define OFF_HNEW (OFF_QKV1 + QKVN)   // feature-major: hnew[j][row], 32*NROWS

__global__ __launch_bounds__(256) void setup_kernel(
    const float* __restrict__ W_x2h, const float* __restrict__ b_x2h,
    const float* __restrict__ W_h2h, const float* __restrict__ b_h2h,
    const float* __restrict__ W_fc2, const float* __restrict__ b_fc2,
    const float* __restrict__ ln_g,  const float* __restrict__ ln_b,
    const float* __restrict__ W_fcsa,const float* __restrict__ b_fcsa,
    const float* __restrict__ W_in,  const float* __restrict__ b_in,
    const float* __restrict__ W_out, const float* __restrict__ b_out,
    float* __restrict__ ws)
{
  int t = blockIdx.x*blockDim.x + threadIdx.x;
  int stride = gridDim.x*blockDim.x;
  for (int i=t;i<1024;i+=stride) ws[OFF_W1+i]   = W_x2h[i];
  for (int i=t;i<1024;i+=stride) ws[OFF_W2+i]   = W_h2h[i];
  for (int i=t;i<3468;i+=stride) ws[OFF_WIN+i]  = W_in[i];
  for (int i=t;i<1024;i+=stride) ws[OFF_WFC2+i] = W_fc2[i];
  for (int i=t;i<32;i+=stride)   ws[OFF_B12+i]  = b_x2h[i] + b_h2h[i];
  for (int i=t;i<102;i+=stride)  ws[OFF_BIN+i]  = b_in[i];
  for (int i=t;i<32;i+=stride)   ws[OFF_BFC2+i] = b_fc2[i];
  for (int i=t;i<32;i+=stride)   ws[OFF_LNG+i]  = ln_g[i];
  for (int i=t;i<32;i+=stride)   ws[OFF_LNB+i]  = ln_b[i];
  // M = W_fcsa (32x34) @ W_out (34x34)
  for (int idx=t; idx<1088; idx+=stride) {
    int j = idx/34, f = idx - j*34;
    float acc = 0.f;
    for (int e=0;e<34;++e)
      acc += W_fcsa[j*34+e] * W_out[e*34+f];
    ws[OFF_M+idx] = acc;
  }
  for (int j=t;j<32;j+=stride){
    float acc = b_fcsa[j];
    for (int e=0;e<34;++e) acc += W_fcsa[j*34+e] * b_out[e];
    ws[OFF_B2+j] = acc;
  }
}

// One launch = attention/update/pred of step stepB + tanh-rnn/qkv of step stepA=stepB+1.
// lane (tid&63) = row; wave id is passed through readfirstlane so ALL weight
// indices are provably wave-uniform -> compiler emits s_load (scalar cache,
// SGPR operands) instead of per-lane global_load for the ~850 weight reads.
__global__ __launch_bounds__(TPB) void step_kernel(
    const float* __restrict__ ws,
    const float* __restrict__ qkvR,     // qkv of step stepB (read)
    float* __restrict__ qkvW,           // qkv of step stepA (write)
    float* __restrict__ hnewG,          // feature-major tanh-state
    const float* __restrict__ x,
    float* __restrict__ out,
    int stepB, int stepA)
{
  const float* W1f   = ws + OFF_W1;
  const float* W2f   = ws + OFF_W2;
  const float* Winf  = ws + OFF_WIN;
  const float* Wfc2f = ws + OFF_WFC2;
  const float* Mf    = ws + OFF_M;
  const float* b12f  = ws + OFF_B12;
  const float* binf  = ws + OFF_BIN;
  const float* b2f   = ws + OFF_B2;
  const float* bfc2f = ws + OFF_BFC2;
  const float* lngf  = ws + OFF_LNG;
  const float* lnbf  = ws + OFF_LNB;

  __shared__ float sS[RPB][13];     // 9 scores
  __shared__ float sO[RPB][35];     // attention output (34)
  __shared__ float sHp[RPB][33];    // h' (post-attention state)
  __shared__ float sG[RPB][33];     // pre-LN fc2 output
  __shared__ float sPred[RPB][33];  // pred (next-step input)
  __shared__ float sHn[RPB][33];    // h_new (tanh output)
  __shared__ float sX[RPB][33];     // staged x chunk (steps 0..9)

  const int tid = threadIdx.x;
  const int lr  = tid & 63;
  const int wu  = __builtin_amdgcn_readfirstlane(tid >> 6);  // wave id, SGPR-uniform
  const int base= blockIdx.x * RPB;
  const int r   = base + lr;
  const int b   = r >> 12;
  const int p   = r & 4095;
  const int gr  = p >> 6, gc = p & 63;
  const int br  = (gr < 1) ? 1 : ((gr > 62) ? 62 : gr);
  const int bc  = (gc < 1) ? 1 : ((gc > 62) ? 62 : gc);

  if (stepB >= 0) {
    // ---- scores: wave wu does neighbor m=wu (wave 0 also m=8) ----
    const int qrow = (b<<12) + (br<<6) + bc;           // query = gathered center
    for (int m = wu; m < 9; m += 8) {
      int dr = m/3 - 1, dc = (m - (m/3)*3) - 1;
      int nr_  = (b<<12) + ((br+dr)<<6) + (bc+dc);
      float acc = 0.f;
      #pragma unroll
      for (int e=0;e<34;++e)
        acc += qkvR[(size_t)e*NROWS + qrow] * qkvR[(size_t)(34+e)*NROWS + nr_];
      sS[lr][m] = acc * 0.1714985851425088f;           // 1/sqrt(34)
    }
    __syncthreads();
    // ---- softmax (redundant per wave) + o: wave wu handles e = 5*wu.. ----
    if (wu < 7) {
      float sc[9]; float mx = -1e30f;
      #pragma unroll
      for (int m=0;m<9;++m){ sc[m]=sS[lr][m]; mx=fmaxf(mx,sc[m]); }
      float sum=0.f;
      #pragma unroll
      for (int m=0;m<9;++m){ sc[m]=__expf(sc[m]-mx); sum+=sc[m]; }
      float inv = 1.f/sum;
      const int e0 = wu*5;
      const int ne = (e0+5<=34)?5:(34-e0);
      float oacc[5] = {0.f,0.f,0.f,0.f,0.f};
      #pragma unroll
      for (int m=0;m<9;++m){
        int dr = m/3 - 1, dc = (m - (m/3)*3) - 1;
        int nr_ = (b<<12) + ((br+dr)<<6) + (bc+dc);
        float wm = sc[m]*inv;
        #pragma unroll
        for (int k=0;k<5;++k)
          if (k<ne) oacc[k] += wm * qkvR[(size_t)(68+e0+k)*NROWS + nr_];
      }
      #pragma unroll
      for (int k=0;k<5;++k) if (k<ne) sO[lr][e0+k]=oacc[k];
    }
    __syncthreads();
    // ---- h' = h_new + o @ M^T + b2 : wave wu -> j = 4wu..4wu+3 ----
    {
      const int j0 = wu*4;
      float a[4];
      #pragma unroll
      for (int jj=0;jj<4;++jj) a[jj] = b2f[j0+jj];
      #pragma unroll
      for (int e=0;e<34;++e){
        float ov = sO[lr][e];
        #pragma unroll
        for (int jj=0;jj<4;++jj) a[jj] += ov * Mf[(j0+jj)*34+e];   // s_load weights
      }
      #pragma unroll
      for (int jj=0;jj<4;++jj)
        sHp[lr][j0+jj] = hnewG[(size_t)(j0+jj)*NROWS + r] + a[jj];
    }
    __syncthreads();
    // ---- g = h' @ Wfc2^T + b ----
    {
      const int j0 = wu*4;
      float g[4];
      #pragma unroll
      for (int jj=0;jj<4;++jj) g[jj] = bfc2f[j0+jj];
      #pragma unroll
      for (int i=0;i<32;++i){
        float hv = sHp[lr][i];
        #pragma unroll
        for (int jj=0;jj<4;++jj) g[jj] += hv * Wfc2f[(j0+jj)*32+i]; // s_load
      }
      #pragma unroll
      for (int jj=0;jj<4;++jj) sG[lr][j0+jj]=g[jj];
    }
    __syncthreads();
    // ---- layernorm -> sPred ----
    {
      float mu=0.f;
      #pragma unroll
      for (int i=0;i<32;++i) mu += sG[lr][i];
      mu *= 0.03125f;
      float var=0.f;
      #pragma unroll
      for (int i=0;i<32;++i){ float d=sG[lr][i]-mu; var += d*d; }
      var *= 0.03125f;
      float rs = rsqrtf(var + 1e-5f);
      const int j0 = wu*4;
      #pragma unroll
      for (int jj=0;jj<4;++jj){
        int j=j0+jj;
        sPred[lr][j] = (sG[lr][j]-mu)*rs*lngf[j] + lnbf[j];
      }
    }
    __syncthreads();
    // ---- coalesced out write (block chunk is 2048 contiguous floats) ----
    {
      size_t obase = ((size_t)stepB*NROWS + base)*32;
      #pragma unroll
      for (int it=0; it<4; ++it){
        int idx = tid + it*TPB;
        out[obase + idx] = sPred[idx>>5][idx&31];
      }
    }
  } else {
    // step 0: h' = 0
    const int j0 = wu*4;
    #pragma unroll
    for (int jj=0;jj<4;++jj) sHp[lr][j0+jj]=0.f;
    __syncthreads();
  }

  if (stepA >= 0) {
    // ---- stage x chunk (coalesced) if this step consumes observations ----
    if (stepA < 10) {
      size_t xbase = ((size_t)stepA*NROWS + base)*32;
      #pragma unroll
      for (int it=0; it<4; ++it){
        int idx = tid + it*TPB;
        sX[idx>>5][idx&31] = x[xbase + idx];
      }
    }
    __syncthreads();
    // ---- h_new = tanh(inp@W1^T + h'@W2^T + b) : wave wu -> j = 4wu..4wu+3 ----
    const int j0 = wu*4;
    float a[4];
    #pragma unroll
    for (int jj=0;jj<4;++jj) a[jj]=b12f[j0+jj];
    if (stepA < 10) {
      #pragma unroll
      for (int i=0;i<32;++i){
        float xv=sX[lr][i], hv=sHp[lr][i];
        #pragma unroll
        for (int jj=0;jj<4;++jj)
          a[jj] += xv*W1f[(j0+jj)*32+i] + hv*W2f[(j0+jj)*32+i];    // s_load
      }
    } else {
      #pragma unroll
      for (int i=0;i<32;++i){
        float xv=sPred[lr][i], hv=sHp[lr][i];
        #pragma unroll
        for (int jj=0;jj<4;++jj)
          a[jj] += xv*W1f[(j0+jj)*32+i] + hv*W2f[(j0+jj)*32+i];    // s_load
      }
    }
    #pragma unroll
    for (int jj=0;jj<4;++jj){
      float tv = tanhf(a[jj]);
      sHn[lr][j0+jj]=tv;
      hnewG[(size_t)(j0+jj)*NROWS + r]=tv;    // coalesced (feature-major)
    }
    __syncthreads();
    // ---- qkv = [h_new, pl] @ W_in^T + b_in : wave wu -> e = 13*wu.. ----
    float hn[32];
    #pragma unroll
    for (int f=0;f<32;++f) hn[f]=sHn[lr][f];
    const float pl0 = gr*0.015625f, pl1 = gc*0.015625f;
    const int e0 = wu*13;
    #pragma unroll
    for (int k=0;k<13;++k){
      int e = e0+k;
      if (e < 102) {
        float acc = binf[e];
        #pragma unroll
        for (int f=0;f<32;++f) acc += hn[f]*Winf[e*34+f];          // s_load
        acc += pl0*Winf[e*34+32] + pl1*Winf[e*34+33];
        qkvW[(size_t)e*NROWS + r] = acc;       // coalesced (feature-major)
      }
    }
  }
}

extern "C" void kernel_launch(void* const* d_in, const int* in_sizes, int n_in,
                              void* d_out, int out_size, void* d_ws, size_t ws_size,
                              hipStream_t stream) {
  const float* x     = (const float*)d_in[0];
  const float* W_x2h = (const float*)d_in[1];
  const float* b_x2h = (const float*)d_in[2];
  const float* W_h2h = (const float*)d_in[3];
  const float* b_h2h = (const float*)d_in[4];
  const float* W_fc2 = (const float*)d_in[5];
  const float* b_fc2 = (const float*)d_in[6];
  const float* ln_g  = (const float*)d_in[7];
  const float* ln_b  = (const float*)d_in[8];
  const float* W_fcsa= (const float*)d_in[9];
  const float* b_fcsa= (const float*)d_in[10];
  const float* W_in  = (const float*)d_in[11];
  const float* b_in  = (const float*)d_in[12];
  const float* W_out = (const float*)d_in[13];
  const float* b_out = (const float*)d_in[14];
  float* ws = (float*)d_ws;
  float* out = (float*)d_out;

  setup_kernel<<<8, 256, 0, stream>>>(W_x2h,b_x2h,W_h2h,b_h2h,W_fc2,b_fc2,ln_g,ln_b,
                                      W_fcsa,b_fcsa,W_in,b_in,W_out,b_out, ws);
  for (int i=0;i<60;++i){
    int stepB = i-1;
    int stepA = (i<=58)? i : -1;
    const float* qR = ws + OFF_QKV0 + (size_t)((i+1)&1)*QKVN;  // qkv of step i-1
    float*       qW = ws + OFF_QKV0 + (size_t)(i&1)*QKVN;      // qkv of step i
    step_kernel<<<NBLK, TPB, 0, stream>>>(ws, qR, qW, ws+OFF_HNEW, x, out, stepB, stepA);
  }
}